// Round 7
// baseline (182.160 us; speedup 1.0000x reference)
//
#include <hip/hip_runtime.h>
#include <math.h>

#define BB 512
#define SS 50
#define EE 128
#define HH 8
#define RR 32
#define NC 5
#define NSEQ 20000
#define NBS (BB*SS)   // 25600
#define LDK 136       // padded bf16 row stride (ushorts) for LDS A-tile

typedef __attribute__((ext_vector_type(8))) __bf16 bf16x8;
typedef __attribute__((ext_vector_type(4))) float f32x4;
typedef __attribute__((ext_vector_type(4))) unsigned short us4;

__device__ __forceinline__ unsigned short f2bf(float f) {
    unsigned int u = __float_as_uint(f);
    unsigned int r = (u + 0x7fffu + ((u >> 16) & 1u)) >> 16;
    return (unsigned short)r;
}
__device__ __forceinline__ float dot4v(const f32x4& a, const float4& b) {
    return a[0]*b.x + a[1]*b.y + a[2]*b.z + a[3]*b.w;
}

// -------------------- prep: weight transpose/convert + seq histogram --------------------
// blocks [0,128): conv (block n: wvT/woT column n); blocks [128,228): hist
__global__ __launch_bounds__(256) void prep_kernel(const float* __restrict__ wv,
                                                   const float* __restrict__ wo,
                                                   unsigned short* __restrict__ wvT,
                                                   unsigned short* __restrict__ woT,
                                                   const int* __restrict__ seq,
                                                   int* __restrict__ hist) {
    const int bid = blockIdx.x, t = threadIdx.x;
    if (bid < 128) {
        const int n = bid;
        if (t < 128) wvT[n*EE + t] = f2bf(wv[t*EE + n]);
        else         woT[n*EE + (t - 128)] = f2bf(wo[(t - 128)*EE + n]);
    } else {
        const int i = (bid - 128) * 256 + t;
        if (i < NBS) atomicAdd(&hist[seq[i]], 1);
    }
}

// single block, 1024 threads: exclusive scan of hist[NSEQ]; working copy to hist,
// pristine copy to hstart (sentinel hstart[NSEQ] = NBS)
__global__ __launch_bounds__(1024) void scan_kernel(int* __restrict__ hist,
                                                    int* __restrict__ hstart) {
    const int t = threadIdx.x;
    const int CH = 20;
    const int base = t * CH;
    int loc[CH];
    int s = 0;
    #pragma unroll
    for (int i = 0; i < CH; ++i) {
        int idx = base + i;
        int v = (idx < NSEQ) ? hist[idx] : 0;
        loc[i] = s; s += v;
    }
    const int lane = t & 63, w = t >> 6;
    int incl = s;
    #pragma unroll
    for (int off = 1; off < 64; off <<= 1) {
        int n = __shfl_up(incl, off);
        if (lane >= off) incl += n;
    }
    __shared__ int wsum[16];
    if (lane == 63) wsum[w] = incl;
    __syncthreads();
    if (t == 0) {
        int acc = 0;
        #pragma unroll
        for (int k = 0; k < 16; ++k) { int v = wsum[k]; wsum[k] = acc; acc += v; }
    }
    __syncthreads();
    const int excl = incl - s + wsum[w];
    #pragma unroll
    for (int i = 0; i < CH; ++i) {
        int idx = base + i;
        if (idx < NSEQ) {
            int e = excl + loc[i];
            hist[idx] = e;
            hstart[idx] = e;
        }
    }
    if (t == 0) hstart[NSEQ] = NBS;
}

__global__ __launch_bounds__(256) void scatter_kernel(const int* __restrict__ seq,
                                                      int* __restrict__ hist,
                                                      int* __restrict__ perm) {
    int i = blockIdx.x * 256 + threadIdx.x;
    if (i < NBS) {
        int pos = atomicAdd(&hist[seq[i]], 1);
        perm[pos] = i;
    }
}

// -------------------- Kernel 1: attention, all-MFMA (unchanged, verified) --------------------
__global__ __launch_bounds__(256, 4) void attn_kernel(
    const int* __restrict__ user,
    const int* __restrict__ neighbor,
    const float* __restrict__ uet,
    const float* __restrict__ wq, const float* __restrict__ bq,
    const float* __restrict__ wk, const float* __restrict__ bk,
    const float* __restrict__ bv, const float* __restrict__ bo,
    const unsigned short* __restrict__ wvT, const unsigned short* __restrict__ woT,
    float* __restrict__ ws_ne2)
{
    __shared__ unsigned short kA[64*LDK];
    __shared__ unsigned short qkvT[16][EE];
    __shared__ float ue[EE];
    __shared__ float qs[EE];
    __shared__ float qkb[HH];
    __shared__ float attn_s[HH][64];
    __shared__ float maskadd[64];

    const int b = blockIdx.x;
    const int t = threadIdx.x;

    if (t < EE) ue[t] = uet[(size_t)user[b]*EE + t];
    if (t < 64) maskadd[t] = (t < SS && neighbor[b*SS + t] > 0) ? 0.f : -1e9f;
    for (int idx = t; idx < SS*32; idx += 256) {
        int s = idx >> 5, g = idx & 31;
        float4 v = ((const float4*)(uet + (size_t)neighbor[b*SS + s]*EE))[g];
        us4 o; o.x = f2bf(v.x); o.y = f2bf(v.y); o.z = f2bf(v.z); o.w = f2bf(v.w);
        *(us4*)&kA[s*LDK + g*4] = o;
    }
    for (int idx = t; idx < 14*LDK; idx += 256) kA[50*LDK + idx] = 0;
    for (int idx = t; idx < 8*EE; idx += 256) qkvT[8 + (idx >> 7)][idx & 127] = 0;
    __syncthreads();

    if (t < EE) {
        float acc = bq[t];
        #pragma unroll 4
        for (int e = 0; e < EE; ++e) acc = fmaf(ue[e], wq[e*EE + t], acc);
        qs[t] = acc;
    }
    __syncthreads();

    {
        const int e = t >> 1, h0 = (t & 1) * 4;
        const float* wrow = wk + e*EE;
        #pragma unroll
        for (int j = 0; j < 4; ++j) {
            int h = h0 + j;
            float acc = 0.f;
            #pragma unroll
            for (int d = 0; d < 16; ++d) acc = fmaf(qs[h*16 + d], wrow[h*16 + d], acc);
            qkvT[h][e] = f2bf(acc);
        }
    }
    if (t < HH) {
        float acc = 0.f;
        #pragma unroll
        for (int d = 0; d < 16; ++d) acc = fmaf(qs[t*16 + d], bk[t*16 + d], acc);
        qkb[t] = acc;
    }
    __syncthreads();

    const int w    = t >> 6;
    const int l    = t & 63;
    const int lrow = l & 15;
    const int kg   = l >> 4;

    bf16x8 a0 = *(const bf16x8*)&kA[(w*16 + lrow)*LDK +  0 + kg*8];
    bf16x8 a1 = *(const bf16x8*)&kA[(w*16 + lrow)*LDK + 32 + kg*8];
    bf16x8 a2 = *(const bf16x8*)&kA[(w*16 + lrow)*LDK + 64 + kg*8];
    bf16x8 a3 = *(const bf16x8*)&kA[(w*16 + lrow)*LDK + 96 + kg*8];

    {
        bf16x8 b0 = *(const bf16x8*)&qkvT[lrow][ 0 + kg*8];
        bf16x8 b1 = *(const bf16x8*)&qkvT[lrow][32 + kg*8];
        bf16x8 b2 = *(const bf16x8*)&qkvT[lrow][64 + kg*8];
        bf16x8 b3 = *(const bf16x8*)&qkvT[lrow][96 + kg*8];
        f32x4 c = {0.f, 0.f, 0.f, 0.f};
        c = __builtin_amdgcn_mfma_f32_16x16x32_bf16(a0, b0, c, 0, 0, 0);
        c = __builtin_amdgcn_mfma_f32_16x16x32_bf16(a1, b1, c, 0, 0, 0);
        c = __builtin_amdgcn_mfma_f32_16x16x32_bf16(a2, b2, c, 0, 0, 0);
        c = __builtin_amdgcn_mfma_f32_16x16x32_bf16(a3, b3, c, 0, 0, 0);
        const int h = lrow;
        if (h < HH) {
            #pragma unroll
            for (int rg = 0; rg < 4; ++rg) {
                const int row = w*16 + kg*4 + rg;
                attn_s[h][row] = (c[rg] + qkb[h]) * 0.25f + maskadd[row];
            }
        }
    }
    __syncthreads();

    if (t < 64) {
        int h = t >> 3, ll = t & 7;
        float mx = -3e38f;
        #pragma unroll
        for (int i = 0; i < 7; ++i) { int s = i*8 + ll; if (s < SS) mx = fmaxf(mx, attn_s[h][s]); }
        mx = fmaxf(mx, __shfl_xor(mx, 1));
        mx = fmaxf(mx, __shfl_xor(mx, 2));
        mx = fmaxf(mx, __shfl_xor(mx, 4));
        float ev[7]; float sm_ = 0.f;
        #pragma unroll
        for (int i = 0; i < 7; ++i) {
            int s = i*8 + ll; ev[i] = 0.f;
            if (s < SS) { ev[i] = expf(attn_s[h][s] - mx); sm_ += ev[i]; }
        }
        sm_ += __shfl_xor(sm_, 1);
        sm_ += __shfl_xor(sm_, 2);
        sm_ += __shfl_xor(sm_, 4);
        float inv = 1.f / sm_;
        #pragma unroll
        for (int i = 0; i < 7; ++i) { int s = i*8 + ll; if (s < SS) attn_s[h][s] = ev[i] * inv; }
    }
    __syncthreads();

    f32x4 acc[8];
    #pragma unroll
    for (int nt = 0; nt < 8; ++nt) {
        const unsigned short* bp = wvT + (nt*16 + lrow)*EE + kg*8;
        bf16x8 b0 = *(const bf16x8*)&bp[0];
        bf16x8 b1 = *(const bf16x8*)&bp[32];
        bf16x8 b2 = *(const bf16x8*)&bp[64];
        bf16x8 b3 = *(const bf16x8*)&bp[96];
        f32x4 c = {0.f, 0.f, 0.f, 0.f};
        c = __builtin_amdgcn_mfma_f32_16x16x32_bf16(a0, b0, c, 0, 0, 0);
        c = __builtin_amdgcn_mfma_f32_16x16x32_bf16(a1, b1, c, 0, 0, 0);
        c = __builtin_amdgcn_mfma_f32_16x16x32_bf16(a2, b2, c, 0, 0, 0);
        c = __builtin_amdgcn_mfma_f32_16x16x32_bf16(a3, b3, c, 0, 0, 0);
        acc[nt] = c;
    }
    #pragma unroll
    for (int nt = 0; nt < 8; ++nt) {
        const int col = nt*16 + lrow;
        const float bvc = bv[col];
        #pragma unroll
        for (int rg = 0; rg < 4; ++rg) {
            const int row = w*16 + kg*4 + rg;
            const float av = (row < SS) ? attn_s[nt][row] : 0.f;
            kA[row*LDK + col] = f2bf((acc[nt][rg] + bvc) * av);
        }
    }
    __syncthreads();

    bf16x8 c0 = *(const bf16x8*)&kA[(w*16 + lrow)*LDK +  0 + kg*8];
    bf16x8 c1 = *(const bf16x8*)&kA[(w*16 + lrow)*LDK + 32 + kg*8];
    bf16x8 c2 = *(const bf16x8*)&kA[(w*16 + lrow)*LDK + 64 + kg*8];
    bf16x8 c3 = *(const bf16x8*)&kA[(w*16 + lrow)*LDK + 96 + kg*8];

    #pragma unroll
    for (int nt = 0; nt < 8; ++nt) {
        const unsigned short* bp = woT + (nt*16 + lrow)*EE + kg*8;
        bf16x8 b0 = *(const bf16x8*)&bp[0];
        bf16x8 b1 = *(const bf16x8*)&bp[32];
        bf16x8 b2 = *(const bf16x8*)&bp[64];
        bf16x8 b3 = *(const bf16x8*)&bp[96];
        f32x4 c = {0.f, 0.f, 0.f, 0.f};
        c = __builtin_amdgcn_mfma_f32_16x16x32_bf16(c0, b0, c, 0, 0, 0);
        c = __builtin_amdgcn_mfma_f32_16x16x32_bf16(c1, b1, c, 0, 0, 0);
        c = __builtin_amdgcn_mfma_f32_16x16x32_bf16(c2, b2, c, 0, 0, 0);
        c = __builtin_amdgcn_mfma_f32_16x16x32_bf16(c3, b3, c, 0, 0, 0);
        const int col = nt*16 + lrow;
        const float boc = bo[col];
        #pragma unroll
        for (int rg = 0; rg < 4; ++rg) {
            const int row = w*16 + kg*4 + rg;
            if (row < SS)
                ws_ne2[((size_t)b*SS + row)*EE + col] = c[rg] + boc;
        }
    }
}

// -------------------- Kernel 2: region, one block per (j, half) --------------------
// blocks [0,NSEQ): np-half (K_iu . ne2, mask folded); [NSEQ,2*NSEQ): ip-half (K_ui . item_emb)
// 16 KB K-panel in 16 VGPRs, barrier-free, low-VGPR for 8 waves/SIMD
__global__ __launch_bounds__(256) void region_kernel(
    const int* __restrict__ neighbor, const int* __restrict__ item,
    const float* __restrict__ ui_lcu, const float* __restrict__ iu_lcu,
    const float* __restrict__ iet, const float* __restrict__ ws_ne2,
    const int* __restrict__ hstart, const int* __restrict__ perm,
    float* __restrict__ ws_np, float* __restrict__ ws_ip)
{
    const int bid = blockIdx.x;
    const bool ip_half = (bid >= NSEQ);
    const int j = ip_half ? (bid - NSEQ) : bid;
    const int start = hstart[j];
    const int end   = hstart[j + 1];
    if (start >= end) return;

    const int t = threadIdx.x;
    const int r = t >> 3, l = t & 7;

    const float* tab = ip_half ? ui_lcu : iu_lcu;
    const f32x4* kg = (const f32x4*)(tab + ((size_t)j*RR + r)*EE);
    f32x4 k0 = kg[l], k1 = kg[l + 8], k2 = kg[l + 16], k3 = kg[l + 24];

    if (ip_half) {
        for (int o = start; o < end; ++o) {
            const int bs = perm[o];
            const int b  = (unsigned)bs / SS;
            const float4* v4 = (const float4*)(iet + (size_t)item[b]*EE);
            float acc = dot4v(k0, v4[l]) + dot4v(k1, v4[l + 8])
                      + dot4v(k2, v4[l + 16]) + dot4v(k3, v4[l + 24]);
            acc += __shfl_xor(acc, 1); acc += __shfl_xor(acc, 2); acc += __shfl_xor(acc, 4);
            if (l == 0) ws_ip[(size_t)bs*RR + r] = acc;
        }
    } else {
        for (int o = start; o < end; ++o) {
            const int bs = perm[o];
            const float4* v4 = (const float4*)(ws_ne2 + (size_t)bs*EE);
            float acc = dot4v(k0, v4[l]) + dot4v(k1, v4[l + 8])
                      + dot4v(k2, v4[l + 16]) + dot4v(k3, v4[l + 24]);
            acc += __shfl_xor(acc, 1); acc += __shfl_xor(acc, 2); acc += __shfl_xor(acc, 4);
            if (l == 0) {
                const float w = (neighbor[bs] > 0) ? 1.f : 0.f;
                ws_np[(size_t)bs*RR + r] = acc * w;
            }
        }
    }
}

// -------------------- Kernel 3: max over s of np*ip, FC, softmax --------------------
__global__ __launch_bounds__(256) void head_kernel(
    const float* __restrict__ ws_np, const float* __restrict__ ws_ip,
    const float* __restrict__ fc_w, const float* __restrict__ fc_b,
    float* __restrict__ out)
{
    __shared__ float part[8][RR];
    __shared__ float urv[RR];
    __shared__ float lg[NC];
    const int b = blockIdx.x, t = threadIdx.x;
    const int r = t & 31, sub = t >> 5;

    float m = -3e38f;
    for (int s = sub; s < SS; s += 8) {
        const size_t idx = ((size_t)b*SS + s)*RR + r;
        m = fmaxf(m, ws_np[idx] * ws_ip[idx]);
    }
    part[sub][r] = m;
    __syncthreads();
    if (t < RR) {
        float mm = part[0][t];
        #pragma unroll
        for (int k = 1; k < 8; ++k) mm = fmaxf(mm, part[k][t]);
        urv[t] = mm;
    }
    __syncthreads();
    if (t < NC) {
        float acc = fc_b[t];
        #pragma unroll
        for (int rr = 0; rr < RR; ++rr) acc = fmaf(urv[rr], fc_w[rr*NC + t], acc);
        lg[t] = acc;
    }
    __syncthreads();
    if (t < NC) {
        float mx = lg[0];
        #pragma unroll
        for (int c = 1; c < NC; ++c) mx = fmaxf(mx, lg[c]);
        float sm = 0.f;
        #pragma unroll
        for (int c = 0; c < NC; ++c) sm += expf(lg[c] - mx);
        out[b*NC + t] = expf(lg[t] - mx) / sm;
    }
}

extern "C" void kernel_launch(void* const* d_in, const int* in_sizes, int n_in,
                              void* d_out, int out_size, void* d_ws, size_t ws_size,
                              hipStream_t stream) {
    const int*   user     = (const int*)d_in[0];
    const int*   item     = (const int*)d_in[1];
    const int*   neighbor = (const int*)d_in[2];
    const int*   seq      = (const int*)d_in[3];
    const float* uet      = (const float*)d_in[4];
    const float* iet      = (const float*)d_in[5];
    const float* ui_lcu   = (const float*)d_in[6];
    const float* iu_lcu   = (const float*)d_in[7];
    const float* wq = (const float*)d_in[8];   const float* bq = (const float*)d_in[9];
    const float* wk = (const float*)d_in[10];  const float* bk = (const float*)d_in[11];
    const float* wv = (const float*)d_in[12];  const float* bv = (const float*)d_in[13];
    const float* wo = (const float*)d_in[14];  const float* bo = (const float*)d_in[15];
    const float* fcw = (const float*)d_in[16]; const float* fcb = (const float*)d_in[17];

    float* ws = (float*)d_ws;
    float* ws_ne2 = ws;                                          // B*S*E f32
    float* ws_np  = ws_ne2 + (size_t)BB*SS*EE;                   // B*S*R f32
    float* ws_ip  = ws_np  + (size_t)BB*SS*RR;                   // B*S*R f32
    unsigned short* wvT = (unsigned short*)(ws_ip + (size_t)BB*SS*RR);  // 128*128 bf16
    unsigned short* woT = wvT + EE*EE;                           // 128*128 bf16
    int*   hist   = (int*)(woT + EE*EE);                         // NSEQ
    int*   hstart = hist + NSEQ;                                 // NSEQ+1
    int*   perm   = hstart + NSEQ + 1;                           // NBS
    float* out = (float*)d_out;

    // ---- prep: conv + hist (fused), scan, scatter ----
    hipMemsetAsync(hist, 0, NSEQ * sizeof(int), stream);
    hipLaunchKernelGGL(prep_kernel, dim3(128 + (NBS + 255)/256), dim3(256), 0, stream,
                       wv, wo, wvT, woT, seq, hist);
    hipLaunchKernelGGL(scan_kernel, dim3(1), dim3(1024), 0, stream, hist, hstart);
    hipLaunchKernelGGL(scatter_kernel, dim3((NBS + 255)/256), dim3(256), 0, stream, seq, hist, perm);

    // ---- attention (all-MFMA) ----
    hipLaunchKernelGGL(attn_kernel, dim3(BB), dim3(256), 0, stream,
                       user, neighbor, uet,
                       wq, bq, wk, bk, bv, bo, wvT, woT, ws_ne2);

    // ---- region: one block per (j, half) ----
    hipLaunchKernelGGL(region_kernel, dim3(2*NSEQ), dim3(256), 0, stream,
                       neighbor, item, ui_lcu, iu_lcu, iet, ws_ne2, hstart, perm,
                       ws_np, ws_ip);

    hipLaunchKernelGGL(head_kernel, dim3(BB), dim3(256), 0, stream,
                       ws_np, ws_ip, fcw, fcb, out);
}